// Round 1
// baseline (323.488 us; speedup 1.0000x reference)
//
#include <hip/hip_runtime.h>
#include <hip/hip_bf16.h>
#include <stdint.h>

// ---------------------------------------------------------------------------
// SNN: x[512,784] -> FC(784->1024)+LIF -> FC(1024->1024)+LIF -> FC(1024->10)+LIF
// T=32, tau=2, vth=1, hard reset to 0. Output = spike counts [512,10].
//
// Layer-0 input is constant over time -> single GEMM + per-neuron 32-step LIF.
// Layer-1 GEMM done in bf16 MFMA with exact 3-way split of W1 (hi+mid+lo),
// spikes are exactly representable in bf16 -> fp32-GEMM-accurate result.
// ---------------------------------------------------------------------------

typedef __bf16 bf16x8 __attribute__((ext_vector_type(8)));
typedef float  f32x4  __attribute__((ext_vector_type(4)));

__device__ __forceinline__ void gload16(const void* g, void* l) {
  __builtin_amdgcn_global_load_lds((const __attribute__((address_space(1))) void*)g,
                                   (__attribute__((address_space(3))) void*)l,
                                   16, 0, 0);
}

// ---------------- W0 transpose: [1024][784] -> [784][1024] ------------------
__global__ __launch_bounds__(256) void transpose_w0(const float* __restrict__ W0,
                                                    float* __restrict__ W0T) {
  __shared__ float t[32][33];
  int k0 = blockIdx.x * 32, o0 = blockIdx.y * 32;
  int lx = threadIdx.x, ly = threadIdx.y;  // 32 x 8
#pragma unroll
  for (int r = 0; r < 32; r += 8) {
    int k = k0 + lx;
    if (k < 784) t[ly + r][lx] = W0[(size_t)(o0 + ly + r) * 784 + k];
  }
  __syncthreads();
#pragma unroll
  for (int r = 0; r < 32; r += 8) {
    int k = k0 + ly + r;
    if (k < 784) W0T[(size_t)k * 1024 + o0 + lx] = t[lx][ly + r];
  }
}

// ---------------- W1 exact 3-way bf16 split, K-concat [1024][3072] ----------
__global__ __launch_bounds__(256) void split_w1(const float* __restrict__ W1,
                                                __hip_bfloat16* __restrict__ Bp) {
  int i = blockIdx.x * 256 + threadIdx.x;  // 1M elements
  int n = i >> 10, k = i & 1023;
  float w = W1[i];
  __hip_bfloat16 h = __float2bfloat16(w);
  float r1 = w - __bfloat162float(h);
  __hip_bfloat16 m = __float2bfloat16(r1);
  float r2 = r1 - __bfloat162float(m);
  __hip_bfloat16 l = __float2bfloat16(r2);   // exact residual: h+m+l == w
  size_t base = (size_t)n * 3072;
  Bp[base + k] = h;
  Bp[base + 1024 + k] = m;
  Bp[base + 2048 + k] = l;
}

// ---------------- layer 0: dot + bias + 32-step LIF -> bf16 spikes ----------
// A[(t*512+b)*1024 + o] = spike (0.0 / 1.0 bf16)
__global__ __launch_bounds__(256) void layer0_fused(const float* __restrict__ x,
                                                    const float* __restrict__ W0T,
                                                    const float* __restrict__ b0,
                                                    __hip_bfloat16* __restrict__ A) {
  int o  = ((blockIdx.x & 3) << 8) + threadIdx.x;   // 0..1023
  int bg = (blockIdx.x >> 2) << 3;                  // batch group of 8
  float acc[8] = {0.f, 0.f, 0.f, 0.f, 0.f, 0.f, 0.f, 0.f};
#pragma unroll 4
  for (int k = 0; k < 784; ++k) {
    float w = W0T[(size_t)k * 1024 + o];
#pragma unroll
    for (int bb = 0; bb < 8; ++bb)
      acc[bb] = fmaf(x[(size_t)(bg + bb) * 784 + k], w, acc[bb]);
  }
  float bias = b0[o];
  unsigned short* As = (unsigned short*)A;
#pragma unroll
  for (int bb = 0; bb < 8; ++bb) {
    float cur = acc[bb] + bias;
    float v = 0.f;
#pragma unroll
    for (int t = 0; t < 32; ++t) {
      v = v + (cur - v) * 0.5f;          // charge (exact /tau, tau=2)
      bool s = (v >= 1.0f);
      As[((size_t)(t * 512 + bg + bb) << 10) + o] = s ? 0x3F80 : 0;  // bf16 1/0
      if (s) v = 0.f;                     // hard reset
    }
  }
}

// ---------------- layer 1 GEMM: A[M,1024](bf16) x Bp[1024,3072] -> C fp32 ---
// m97-style: 128x128 tile, BK=32, global_load_lds(16B), XOR quad swizzle.
__global__ __launch_bounds__(256, 2) void gemm1(const __hip_bfloat16* __restrict__ A,
                                                const __hip_bfloat16* __restrict__ Bp,
                                                float* __restrict__ C) {
  __shared__ __align__(16) __hip_bfloat16 As[128 * 32];
  __shared__ __align__(16) __hip_bfloat16 Bs[128 * 32];
  const int tid = threadIdx.x;
  const int wave = tid >> 6, lane = tid & 63, quad = lane >> 4, l16 = lane & 15;
  const int wm = (wave >> 1) * 64, wn = (wave & 1) * 64;
  const int mbase = blockIdx.x * 128, nbase = blockIdx.y * 128;

  const int srow = lane >> 2;                 // staging row within 16-row group
  const int gq   = (lane & 3) ^ ((lane >> 3) & 3);  // swizzled source quad
  const int swz  = (l16 >> 1) & 3;            // reader-side swizzle

  f32x4 acc[4][4] = {};

  for (int kk = 0; kk < 3072; kk += 32) {
    const int kA = kk & 1023;                 // fold K back into [0,1024) for A
#pragma unroll
    for (int r = 0; r < 2; ++r) {
      int grp = wave * 2 + r;                 // 16-row group 0..7
      const __hip_bfloat16* ag =
          A + (size_t)(mbase + grp * 16 + srow) * 1024 + kA + gq * 8;
      gload16(ag, (char*)As + grp * 1024);
      const __hip_bfloat16* bg =
          Bp + (size_t)(nbase + grp * 16 + srow) * 3072 + kk + gq * 8;
      gload16(bg, (char*)Bs + grp * 1024);
    }
    __syncthreads();

    const __bf16* Ab = (const __bf16*)As;
    const __bf16* Bb = (const __bf16*)Bs;
    bf16x8 af[4], bfr[4];
#pragma unroll
    for (int i = 0; i < 4; ++i)
      af[i] = *(const bf16x8*)(Ab + (wm + i * 16 + l16) * 32 + ((quad ^ swz) * 8));
#pragma unroll
    for (int j = 0; j < 4; ++j)
      bfr[j] = *(const bf16x8*)(Bb + (wn + j * 16 + l16) * 32 + ((quad ^ swz) * 8));
#pragma unroll
    for (int i = 0; i < 4; ++i)
#pragma unroll
      for (int j = 0; j < 4; ++j)
        acc[i][j] = __builtin_amdgcn_mfma_f32_16x16x32_bf16(af[i], bfr[j], acc[i][j], 0, 0, 0);
    __syncthreads();
  }

#pragma unroll
  for (int i = 0; i < 4; ++i)
#pragma unroll
    for (int j = 0; j < 4; ++j)
#pragma unroll
      for (int r = 0; r < 4; ++r) {
        int m = mbase + wm + i * 16 + quad * 4 + r;
        int n = nbase + wn + j * 16 + l16;
        C[(size_t)m * 1024 + n] = acc[i][j][r];
      }
}

// ---------------- layer 1 LIF over a chunk of timesteps ---------------------
__global__ __launch_bounds__(256) void lif1(const float* __restrict__ cur1,
                                            const float* __restrict__ b1,
                                            unsigned* __restrict__ s1w,
                                            float* __restrict__ vst,
                                            int t0, int tc) {
  int idx = blockIdx.x * 256 + threadIdx.x;   // b*1024 + o, 524288 total
  float v; unsigned word;
  if (t0 == 0) { v = 0.f; word = 0u; } else { v = vst[idx]; word = s1w[idx]; }
  float bias = b1[idx & 1023];
  for (int t = 0; t < tc; ++t) {
    float xc = cur1[(size_t)t * 524288 + idx] + bias;
    v = v + (xc - v) * 0.5f;
    if (v >= 1.0f) { word |= (1u << (t0 + t)); v = 0.f; }
  }
  s1w[idx] = word;
  vst[idx] = v;
}

// ---------------- layer 2: fused FC + LIF + count, one block per batch ------
__global__ __launch_bounds__(320) void layer2_fused(const unsigned* __restrict__ s1w,
                                                    const float* __restrict__ W2,
                                                    const float* __restrict__ b2,
                                                    float* __restrict__ out) {
  __shared__ unsigned sw[1024];
  __shared__ float sW2[10 * 1025];            // pad 1025 -> conflict-free
  __shared__ float scur[320];
  int b = blockIdx.x, tid = threadIdx.x;
  for (int i = tid; i < 1024; i += 320) sw[i] = s1w[(size_t)b * 1024 + i];
  for (int i = tid; i < 10240; i += 320) sW2[(i >> 10) * 1025 + (i & 1023)] = W2[i];
  __syncthreads();

  int t = tid / 10, o = tid - t * 10;         // 32 x 10 = 320
  float acc = 0.f;
#pragma unroll 4
  for (int k = 0; k < 1024; ++k) {
    float w = sW2[o * 1025 + k];
    unsigned wd = sw[k];
    acc += ((wd >> t) & 1u) ? w : 0.f;
  }
  scur[t * 10 + o] = acc;
  __syncthreads();

  if (tid < 10) {
    float v = 0.f, cnt = 0.f, bias = b2[tid];
#pragma unroll
    for (int tt = 0; tt < 32; ++tt) {
      float xc = scur[tt * 10 + tid] + bias;
      v = v + (xc - v) * 0.5f;
      if (v >= 1.f) { cnt += 1.f; v = 0.f; }
    }
    out[(size_t)b * 10 + tid] = cnt;
  }
}

// ---------------------------------------------------------------------------
extern "C" void kernel_launch(void* const* d_in, const int* in_sizes, int n_in,
                              void* d_out, int out_size, void* d_ws, size_t ws_size,
                              hipStream_t stream) {
  const float* x  = (const float*)d_in[0];   // [512,784]
  const float* W0 = (const float*)d_in[1];   // [1024,784]
  const float* b0 = (const float*)d_in[2];   // [1024]
  const float* W1 = (const float*)d_in[3];   // [1024,1024]
  const float* b1 = (const float*)d_in[4];   // [1024]
  const float* W2 = (const float*)d_in[5];   // [10,1024]
  const float* b2 = (const float*)d_in[6];   // [10]
  float* out = (float*)d_out;                // [512,10]

  char* ws = (char*)d_ws;
  size_t off = 0;
  auto alloc = [&](size_t bytes) -> char* {
    char* p = ws + off;
    off += (bytes + 255) & ~(size_t)255;
    return p;
  };
  float*          W0T = (float*)alloc((size_t)784 * 1024 * 4);          // 3.2 MB
  __hip_bfloat16* Bp  = (__hip_bfloat16*)alloc((size_t)1024 * 3072 * 2); // 6 MB
  __hip_bfloat16* Ab  = (__hip_bfloat16*)alloc((size_t)16384 * 1024 * 2);// 32 MB
  unsigned*       s1w = (unsigned*)alloc((size_t)512 * 1024 * 4);       // 2 MB
  float*          vst = (float*)alloc((size_t)512 * 1024 * 4);          // 2 MB

  size_t rem = (ws_size > off) ? (ws_size - off) : 0;
  int TC = 32;                                   // timesteps per GEMM chunk
  while (TC > 1 && rem < (size_t)TC * 512 * 1024 * 4) TC >>= 1;
  float* cur1 = (float*)(ws + off);              // [TC*512][1024] fp32

  transpose_w0<<<dim3(25, 32), dim3(32, 8), 0, stream>>>(W0, W0T);
  split_w1<<<4096, 256, 0, stream>>>(W1, Bp);
  layer0_fused<<<256, 256, 0, stream>>>(x, W0T, b0, Ab);

  int nc = 32 / TC;
  for (int c = 0; c < nc; ++c) {
    gemm1<<<dim3(TC * 512 / 128, 8), 256, 0, stream>>>(
        Ab + (size_t)c * TC * 512 * 1024, Bp, cur1);
    lif1<<<2048, 256, 0, stream>>>(cur1, b1, s1w, vst, c * TC, TC);
  }
  layer2_fused<<<512, 320, 0, stream>>>(s1w, W2, b2, out);
}

// Round 2
// 215.873 us; speedup vs baseline: 1.4985x; 1.4985x over previous
//
#include <hip/hip_runtime.h>
#include <stdint.h>

// ---------------------------------------------------------------------------
// SNN: x[512,784] -> FC(784->1024)+LIF -> FC(1024->1024)+LIF -> FC(1024->10)+LIF
// T=32, tau=2 (charge v=(v+cur)/2), vth=1, hard reset to 0. Out = counts [512,10].
//
// Key fact: layer-0 input current is CONSTANT over time, so only neurons with
// cur0 > ~1 ever spike (~3% with Xavier init). Downstream layers are computed
// as exact sparse sums over the active sets (skipping exact-0.0 terms is
// bit-identical to a dense ascending-k fp32 sum). No GEMM, no MFMA needed.
// All spike logic replicates the reference recurrence exactly in fp32.
// ---------------------------------------------------------------------------

// ---------------- generic 32x32 tiled transpose: src[R][C] -> dst[C][R] -----
__global__ __launch_bounds__(256) void transpose_k(const float* __restrict__ src,
                                                   float* __restrict__ dst,
                                                   int R, int C) {
  __shared__ float t[32][33];
  int c0 = blockIdx.x * 32, r0 = blockIdx.y * 32;
  int lx = threadIdx.x, ly = threadIdx.y;  // 32 x 8
#pragma unroll
  for (int i = 0; i < 32; i += 8) {
    int r = r0 + ly + i, c = c0 + lx;
    if (r < R && c < C) t[ly + i][lx] = src[(size_t)r * C + c];
  }
  __syncthreads();
#pragma unroll
  for (int i = 0; i < 32; i += 8) {
    int c = c0 + ly + i, r = r0 + lx;
    if (c < C && r < R) dst[(size_t)c * R + r] = t[lx][ly + i];
  }
}

// ---------------- layer-0 currents: cur0[b][o] = x[b,:] . W0T[:,o] ----------
// 256 blocks: 4 o-tiles x 64 batch-groups of 8. W0T reads coalesced; x reads
// wave-uniform (scalar path). 8 independent FMA chains for ILP.
__global__ __launch_bounds__(256) void cur0_k(const float* __restrict__ x,
                                              const float* __restrict__ W0T,
                                              float* __restrict__ cur0) {
  int o = ((blockIdx.x & 3) << 8) + threadIdx.x;  // 0..1023
  int bg = (blockIdx.x >> 2) << 3;                // batch group of 8
  float acc[8] = {};
#pragma unroll 8
  for (int k = 0; k < 784; ++k) {
    float w = W0T[(size_t)k * 1024 + o];
#pragma unroll
    for (int bb = 0; bb < 8; ++bb)
      acc[bb] = fmaf(x[(size_t)(bg + bb) * 784 + k], w, acc[bb]);
  }
#pragma unroll
  for (int bb = 0; bb < 8; ++bb)
    cur0[(size_t)(bg + bb) * 1024 + o] = acc[bb];
}

// ---------------- layer-0 LIF + deterministic compaction --------------------
// One block per batch b (1024 threads = 16 waves). Exact 32-step LIF on the
// constant current; active neurons (word != 0) compacted in ascending-o order
// via ballot + prefix (no atomics -> deterministic).
__global__ __launch_bounds__(1024) void compact0_k(const float* __restrict__ cur0,
                                                   const float* __restrict__ b0,
                                                   unsigned* __restrict__ lidx,
                                                   unsigned* __restrict__ lwrd,
                                                   int* __restrict__ n0) {
  int b = blockIdx.x, o = threadIdx.x;
  float cur = cur0[(size_t)b * 1024 + o] + b0[o];
  float v = 0.f;
  unsigned word = 0u;
#pragma unroll
  for (int t = 0; t < 32; ++t) {
    v = v + (cur - v) * 0.5f;            // exact: /2.0 == *0.5f
    if (v >= 1.0f) { word |= 1u << t; v = 0.f; }
  }
  bool act = (word != 0u);
  unsigned long long m = __ballot(act);
  __shared__ int wtot[16], wbase[16];
  int wave = o >> 6, lane = o & 63;
  if (lane == 0) wtot[wave] = __popcll(m);
  __syncthreads();
  if (o == 0) {
    int s = 0;
#pragma unroll
    for (int i = 0; i < 16; ++i) { wbase[i] = s; s += wtot[i]; }
    n0[b] = s;
  }
  __syncthreads();
  if (act) {
    int pos = wbase[wave] + __popcll(m & ((1ull << lane) - 1ull));
    lidx[(size_t)b * 1024 + pos] = (unsigned)o;
    lwrd[(size_t)b * 1024 + pos] = word;
  }
}

// ---------------- layer-1: sparse currents + LIF + compaction ---------------
// One block per batch (1024 threads, thread = output neuron o).
// cur1[t] = sum over active layer-0 neurons k (bit t set) of W1T[k][o],
// accumulated in ascending-k order == dense ascending sum exactly.
__global__ __launch_bounds__(1024) void layer1_k(const unsigned* __restrict__ lidx,
                                                 const unsigned* __restrict__ lwrd,
                                                 const int* __restrict__ n0,
                                                 const float* __restrict__ W1T,
                                                 const float* __restrict__ b1,
                                                 unsigned* __restrict__ l2idx,
                                                 unsigned* __restrict__ l2wrd,
                                                 int* __restrict__ n2) {
  __shared__ unsigned sidx[1024], swrd[1024];
  int b = blockIdx.x, o = threadIdx.x;
  int nb = n0[b];
  if (o < nb) {
    sidx[o] = lidx[(size_t)b * 1024 + o];
    swrd[o] = lwrd[(size_t)b * 1024 + o];
  }
  __syncthreads();

  float cur[32] = {};
  // manual prefetch of the coalesced W1T column value
  float w = (nb > 0) ? W1T[(size_t)sidx[0] * 1024 + o] : 0.f;
  for (int j = 0; j < nb; ++j) {
    float wn = (j + 1 < nb) ? W1T[(size_t)sidx[j + 1] * 1024 + o] : 0.f;
    unsigned wd = swrd[j];
#pragma unroll
    for (int t = 0; t < 32; ++t)
      cur[t] += ((wd >> t) & 1u) ? w : 0.f;
    w = wn;
  }

  float bias = b1[o];
  float v = 0.f;
  unsigned word = 0u;
#pragma unroll
  for (int t = 0; t < 32; ++t) {
    float xc = cur[t] + bias;
    v = v + (xc - v) * 0.5f;
    if (v >= 1.0f) { word |= 1u << t; v = 0.f; }
  }

  bool act = (word != 0u);
  unsigned long long m = __ballot(act);
  __shared__ int wtot[16], wbase[16];
  int wave = o >> 6, lane = o & 63;
  if (lane == 0) wtot[wave] = __popcll(m);
  __syncthreads();
  if (o == 0) {
    int s = 0;
#pragma unroll
    for (int i = 0; i < 16; ++i) { wbase[i] = s; s += wtot[i]; }
    n2[b] = s;
  }
  __syncthreads();
  if (act) {
    int pos = wbase[wave] + __popcll(m & ((1ull << lane) - 1ull));
    l2idx[(size_t)b * 1024 + pos] = (unsigned)o;
    l2wrd[(size_t)b * 1024 + pos] = word;
  }
}

// ---------------- layer-2: sparse FC + LIF + count --------------------------
// One block per batch, 320 threads = (t=0..31) x (c=0..9).
__global__ __launch_bounds__(320) void layer2_k(const unsigned* __restrict__ l2idx,
                                                const unsigned* __restrict__ l2wrd,
                                                const int* __restrict__ n2,
                                                const float* __restrict__ W2,
                                                const float* __restrict__ b2,
                                                float* __restrict__ out) {
  __shared__ float sW2[10 * 1025];   // +1 pad -> conflict-free
  __shared__ unsigned sidx[1024], swrd[1024];
  __shared__ float scur[320];
  int b = blockIdx.x, tid = threadIdx.x;
  int m = n2[b];
  for (int i = tid; i < 10240; i += 320)
    sW2[(i >> 10) * 1025 + (i & 1023)] = W2[i];
  for (int i = tid; i < m; i += 320) {
    sidx[i] = l2idx[(size_t)b * 1024 + i];
    swrd[i] = l2wrd[(size_t)b * 1024 + i];
  }
  __syncthreads();

  int t = tid / 10, c = tid - t * 10;  // 32 x 10
  float acc = 0.f;
  for (int j = 0; j < m; ++j) {
    unsigned wd = swrd[j];
    float wv = sW2[c * 1025 + sidx[j]];
    acc += ((wd >> t) & 1u) ? wv : 0.f;  // select, no divergence
  }
  scur[t * 10 + c] = acc;
  __syncthreads();

  if (tid < 10) {
    float v = 0.f, cnt = 0.f, bias = b2[tid];
#pragma unroll
    for (int tt = 0; tt < 32; ++tt) {
      float xc = scur[tt * 10 + tid] + bias;
      v = v + (xc - v) * 0.5f;
      if (v >= 1.0f) { cnt += 1.f; v = 0.f; }
    }
    out[(size_t)b * 10 + tid] = cnt;
  }
}

// ---------------------------------------------------------------------------
extern "C" void kernel_launch(void* const* d_in, const int* in_sizes, int n_in,
                              void* d_out, int out_size, void* d_ws, size_t ws_size,
                              hipStream_t stream) {
  const float* x  = (const float*)d_in[0];   // [512,784]
  const float* W0 = (const float*)d_in[1];   // [1024,784]
  const float* b0 = (const float*)d_in[2];   // [1024]
  const float* W1 = (const float*)d_in[3];   // [1024,1024]
  const float* b1 = (const float*)d_in[4];   // [1024]
  const float* W2 = (const float*)d_in[5];   // [10,1024]
  const float* b2 = (const float*)d_in[6];   // [10]
  float* out = (float*)d_out;                // [512,10]

  char* ws = (char*)d_ws;
  size_t off = 0;
  auto alloc = [&](size_t bytes) -> char* {
    char* p = ws + off;
    off += (bytes + 255) & ~(size_t)255;
    return p;
  };
  float*    W0T   = (float*)alloc((size_t)784 * 1024 * 4);    // 3.2 MB
  float*    W1T   = (float*)alloc((size_t)1024 * 1024 * 4);   // 4.2 MB
  float*    cur0  = (float*)alloc((size_t)512 * 1024 * 4);    // 2.1 MB
  unsigned* lidx  = (unsigned*)alloc((size_t)512 * 1024 * 4); // 2.1 MB
  unsigned* lwrd  = (unsigned*)alloc((size_t)512 * 1024 * 4);
  int*      n0    = (int*)alloc((size_t)512 * 4);
  unsigned* l2idx = (unsigned*)alloc((size_t)512 * 1024 * 4);
  unsigned* l2wrd = (unsigned*)alloc((size_t)512 * 1024 * 4);
  int*      n2    = (int*)alloc((size_t)512 * 4);
  (void)ws_size;

  transpose_k<<<dim3(25, 32), dim3(32, 8), 0, stream>>>(W0, W0T, 1024, 784);
  transpose_k<<<dim3(32, 32), dim3(32, 8), 0, stream>>>(W1, W1T, 1024, 1024);
  cur0_k<<<256, 256, 0, stream>>>(x, W0T, cur0);
  compact0_k<<<512, 1024, 0, stream>>>(cur0, b0, lidx, lwrd, n0);
  layer1_k<<<512, 1024, 0, stream>>>(lidx, lwrd, n0, W1T, b1, l2idx, l2wrd, n2);
  layer2_k<<<512, 320, 0, stream>>>(l2idx, l2wrd, n2, W2, b2, out);
}